// Round 1
// baseline (1308.380 us; speedup 1.0000x reference)
//
#include <hip/hip_runtime.h>
#include <hip/hip_bf16.h>

// MoE expert MLP: y[b] = (gelu(x[b] @ W1[e] + b1[e]) @ W2[e] + b2[e]) * w[b]
// B=8, S=4096, D=1024, F=4096, E=8.  All inputs f32; compute in bf16 MFMA.

#define B_ 8
#define S_ 4096
#define D_ 1024
#define F_ 4096
#define E_ 8

typedef __bf16 bf16x8 __attribute__((ext_vector_type(8)));
typedef float f32x4 __attribute__((ext_vector_type(4)));

__device__ __forceinline__ unsigned short f2bf(float f) {
  unsigned u = __float_as_uint(f);
  u += 0x7FFFu + ((u >> 16) & 1u);   // round-to-nearest-even
  return (unsigned short)(u >> 16);
}

// global -> LDS direct copy, 16B/lane. LDS dest must be wave-uniform base
// (HW adds lane*16). Global src is per-lane.
#define GLD16(g, l) __builtin_amdgcn_global_load_lds(                         \
    (const __attribute__((address_space(1))) unsigned int*)(g),              \
    (__attribute__((address_space(3))) unsigned int*)(l), 16, 0, 0)

// ---------------------------------------------------------------------------
// Transpose + f32->bf16 convert:  src (nmat, R, C) f32  ->  dst (nmat, C, R) bf16
// ---------------------------------------------------------------------------
__global__ __launch_bounds__(256) void transpose_cvt_kernel(
    const float* __restrict__ src, unsigned short* __restrict__ dst,
    int R, int C) {
  __shared__ float t[32][33];
  const float* s = src + (size_t)blockIdx.z * R * C;
  unsigned short* d = dst + (size_t)blockIdx.z * R * C;
  int c0 = blockIdx.x * 32, r0 = blockIdx.y * 32;
  int x = threadIdx.x, y = threadIdx.y;      // 32 x 8
#pragma unroll
  for (int j = 0; j < 32; j += 8)
    t[y + j][x] = s[(size_t)(r0 + y + j) * C + (c0 + x)];
  __syncthreads();
#pragma unroll
  for (int j = 0; j < 32; j += 8)
    d[(size_t)(c0 + y + j) * R + (r0 + x)] = f2bf(t[x][y + j]);
}

// ---------------------------------------------------------------------------
// GEMM1: H[r][f] = gelu( sum_k X[r][k] * W1t[e][f][k] + b1[e][f] )   (bf16 out)
//   X f32 [32768][1024] (row-major), W1t bf16 [E][F][D]
//   tile 128x128, BK=64, 4 waves (2x2), mfma 16x16x32 bf16
//   LDS layout: [row][8 chunks of 16B], chunk cc holds global chunk cc^(row&7)
// ---------------------------------------------------------------------------
__global__ __launch_bounds__(256) void gemm1_kernel(
    const float* __restrict__ X, const unsigned short* __restrict__ W1t,
    const float* __restrict__ b1, const int* __restrict__ eidx,
    unsigned short* __restrict__ H, int row0) {
  __shared__ __align__(16) char smem[32768];
  char* As = smem;            // 128 x 64 bf16 = 16KB
  char* Bs = smem + 16384;    // 128 x 64 bf16 = 16KB

  const int tid = threadIdx.x;
  const int lane = tid & 63;
  const int wave = tid >> 6;
  const int wr = wave >> 1, wc = wave & 1;
  const int l15 = lane & 15, lhi = lane >> 4;

  const int gr0 = row0 + blockIdx.x * 128;      // global row base (within B*S)
  const int bat = gr0 >> 12;                    // / 4096
  const int e = eidx[bat];
  const int col0 = blockIdx.y * 128;

  const float* Abase = X + (size_t)gr0 * D_;
  const unsigned short* Bbase = W1t + (size_t)e * F_ * D_ + (size_t)col0 * D_;

  f32x4 acc[4][4] = {};

  for (int kt = 0; kt < D_; kt += 64) {
    // -- stage B (bf16) via global_load_lds, source pre-swizzled --
#pragma unroll
    for (int i = 0; i < 4; ++i) {
      int cbase = i * 256 + (wave << 6);        // wave-uniform chunk base
      int c = cbase + lane;
      int r = c >> 3, cc = c & 7;
      int gc = cc ^ (r & 7);
      GLD16(Bbase + (size_t)r * D_ + kt + gc * 8, Bs + (size_t)cbase * 16);
    }
    // -- stage A: f32 -> bf16 reg-staged, swizzled ds_write --
#pragma unroll
    for (int i = 0; i < 8; ++i) {
      int q = i * 256 + tid;                    // quad id 0..2047
      int r = q >> 4, qc = q & 15;
      float4 v = *(const float4*)(Abase + (size_t)r * D_ + kt + qc * 4);
      unsigned lo = (unsigned)f2bf(v.x) | ((unsigned)f2bf(v.y) << 16);
      unsigned hi = (unsigned)f2bf(v.z) | ((unsigned)f2bf(v.w) << 16);
      int addr = r * 128 + (((qc >> 1) ^ (r & 7)) << 4) + (qc & 1) * 8;
      *(uint2*)(As + addr) = make_uint2(lo, hi);
    }
    __syncthreads();
    // -- compute: 2 k-steps x 16 MFMA --
#pragma unroll
    for (int kk = 0; kk < 2; ++kk) {
      bf16x8 a[4], b[4];
#pragma unroll
      for (int m = 0; m < 4; ++m) {
        int r = wr * 64 + m * 16 + l15;
        int gc = kk * 4 + lhi;
        a[m] = *(const bf16x8*)(As + r * 128 + ((gc ^ (r & 7)) << 4));
      }
#pragma unroll
      for (int n = 0; n < 4; ++n) {
        int r = wc * 64 + n * 16 + l15;
        int gc = kk * 4 + lhi;
        b[n] = *(const bf16x8*)(Bs + r * 128 + ((gc ^ (r & 7)) << 4));
      }
#pragma unroll
      for (int m = 0; m < 4; ++m)
#pragma unroll
        for (int n = 0; n < 4; ++n)
          acc[m][n] = __builtin_amdgcn_mfma_f32_16x16x32_bf16(
              a[m], b[n], acc[m][n], 0, 0, 0);
    }
    __syncthreads();
  }

  // epilogue: + b1, exact gelu, bf16 store to H (chunk-local rows)
#pragma unroll
  for (int n = 0; n < 4; ++n) {
    int col = col0 + wc * 64 + n * 16 + l15;
    float bias = b1[(size_t)e * F_ + col];
#pragma unroll
    for (int m = 0; m < 4; ++m) {
      int rbase = blockIdx.x * 128 + wr * 64 + m * 16 + lhi * 4;
#pragma unroll
      for (int r = 0; r < 4; ++r) {
        float v = acc[m][n][r] + bias;
        v = 0.5f * v * (1.0f + erff(v * 0.70710678118654752f));
        H[(size_t)(rbase + r) * F_ + col] = f2bf(v);
      }
    }
  }
}

// ---------------------------------------------------------------------------
// GEMM2: Y[r][d] = ( sum_f H[r][f] * W2t[e][d][f] + b2[e][d] ) * w[b]  (f32 out)
//   H bf16 [chunk][F], W2t bf16 [E][D][F]
// ---------------------------------------------------------------------------
__global__ __launch_bounds__(256) void gemm2_kernel(
    const unsigned short* __restrict__ H, const unsigned short* __restrict__ W2t,
    const float* __restrict__ b2, const int* __restrict__ eidx,
    const float* __restrict__ ew, float* __restrict__ Y, int row0) {
  __shared__ __align__(16) char smem[32768];
  char* As = smem;
  char* Bs = smem + 16384;

  const int tid = threadIdx.x;
  const int lane = tid & 63;
  const int wave = tid >> 6;
  const int wr = wave >> 1, wc = wave & 1;
  const int l15 = lane & 15, lhi = lane >> 4;

  const int gr0 = row0 + blockIdx.x * 128;
  const int bat = gr0 >> 12;
  const int e = eidx[bat];
  const float scale = ew[bat];
  const int col0 = blockIdx.y * 128;

  const unsigned short* Abase = H + (size_t)(blockIdx.x * 128) * F_;
  const unsigned short* Bbase = W2t + (size_t)e * D_ * F_ + (size_t)col0 * F_;

  f32x4 acc[4][4] = {};

  for (int kt = 0; kt < F_; kt += 64) {
#pragma unroll
    for (int i = 0; i < 4; ++i) {
      int cbase = i * 256 + (wave << 6);
      int c = cbase + lane;
      int r = c >> 3, cc = c & 7;
      int gc = cc ^ (r & 7);
      GLD16(Bbase + (size_t)r * F_ + kt + gc * 8, Bs + (size_t)cbase * 16);
      GLD16(Abase + (size_t)r * F_ + kt + gc * 8, As + (size_t)cbase * 16);
    }
    __syncthreads();
#pragma unroll
    for (int kk = 0; kk < 2; ++kk) {
      bf16x8 a[4], b[4];
#pragma unroll
      for (int m = 0; m < 4; ++m) {
        int r = wr * 64 + m * 16 + l15;
        int gc = kk * 4 + lhi;
        a[m] = *(const bf16x8*)(As + r * 128 + ((gc ^ (r & 7)) << 4));
      }
#pragma unroll
      for (int n = 0; n < 4; ++n) {
        int r = wc * 64 + n * 16 + l15;
        int gc = kk * 4 + lhi;
        b[n] = *(const bf16x8*)(Bs + r * 128 + ((gc ^ (r & 7)) << 4));
      }
#pragma unroll
      for (int m = 0; m < 4; ++m)
#pragma unroll
        for (int n = 0; n < 4; ++n)
          acc[m][n] = __builtin_amdgcn_mfma_f32_16x16x32_bf16(
              a[m], b[n], acc[m][n], 0, 0, 0);
    }
    __syncthreads();
  }

#pragma unroll
  for (int n = 0; n < 4; ++n) {
    int col = col0 + wc * 64 + n * 16 + l15;
    float bias = b2[(size_t)e * D_ + col];
#pragma unroll
    for (int m = 0; m < 4; ++m) {
      int grbase = gr0 + wr * 64 + m * 16 + lhi * 4;
#pragma unroll
      for (int r = 0; r < 4; ++r)
        Y[(size_t)(grbase + r) * D_ + col] = (acc[m][n][r] + bias) * scale;
    }
  }
}

// ---------------------------------------------------------------------------
extern "C" void kernel_launch(void* const* d_in, const int* in_sizes, int n_in,
                              void* d_out, int out_size, void* d_ws,
                              size_t ws_size, hipStream_t stream) {
  const float* x = (const float*)d_in[0];
  const float* ew = (const float*)d_in[1];
  const float* W1 = (const float*)d_in[2];
  const float* b1 = (const float*)d_in[3];
  const float* W2 = (const float*)d_in[4];
  const float* b2 = (const float*)d_in[5];
  const int* eidx = (const int*)d_in[6];
  float* out = (float*)d_out;

  char* ws = (char*)d_ws;
  const size_t WT = (size_t)E_ * F_ * D_ * 2;  // 64 MiB per transposed weight
  unsigned short* w1t = (unsigned short*)ws;
  unsigned short* w2t = (unsigned short*)(ws + WT);
  unsigned short* hbuf = (unsigned short*)(ws + 2 * WT);

  // Pre-transpose + bf16-convert weights: W1 (E,D,F)->(E,F,D), W2 (E,F,D)->(E,D,F)
  transpose_cvt_kernel<<<dim3(F_ / 32, D_ / 32, E_), dim3(32, 8), 0, stream>>>(
      W1, w1t, D_, F_);
  transpose_cvt_kernel<<<dim3(D_ / 32, F_ / 32, E_), dim3(32, 8), 0, stream>>>(
      W2, w2t, F_, D_);

  const long total_rows = (long)B_ * S_;  // 32768
  long hcap = ((long)ws_size - 2 * (long)WT) / ((long)F_ * 2);
  long chunk = (hcap / 128) * 128;
  if (chunk > total_rows) chunk = total_rows;
  if (chunk < 128) chunk = 128;  // minimal fallback

  for (long r0 = 0; r0 < total_rows; r0 += chunk) {
    long nr = total_rows - r0;
    if (nr > chunk) nr = chunk;
    gemm1_kernel<<<dim3(nr / 128, F_ / 128), 256, 0, stream>>>(
        x, w1t, b1, eidx, hbuf, (int)r0);
    gemm2_kernel<<<dim3(nr / 128, D_ / 128), 256, 0, stream>>>(
        hbuf, w2t, b2, eidx, ew, out, (int)r0);
  }
}

// Round 2
// 1150.323 us; speedup vs baseline: 1.1374x; 1.1374x over previous
//
#include <hip/hip_runtime.h>
#include <hip/hip_bf16.h>

// MoE expert MLP: y[b] = (gelu(x[b] @ W1[e] + b1[e]) @ W2[e] + b2[e]) * w[b]
// B=8, S=4096, D=1024, F=4096, E=8.  All inputs f32; compute in bf16 MFMA.

#define B_ 8
#define S_ 4096
#define D_ 1024
#define F_ 4096
#define E_ 8

typedef __bf16 bf16x8 __attribute__((ext_vector_type(8)));
typedef float f32x4 __attribute__((ext_vector_type(4)));

__device__ __forceinline__ unsigned short f2bf(float f) {
  unsigned u = __float_as_uint(f);
  u += 0x7FFFu + ((u >> 16) & 1u);   // round-to-nearest-even
  return (unsigned short)(u >> 16);
}

// global -> LDS direct copy, 16B/lane. LDS dest must be wave-uniform base
// (HW adds lane*16). Global src is per-lane.
#define GLD16(g, l) __builtin_amdgcn_global_load_lds(                         \
    (const __attribute__((address_space(1))) unsigned int*)(g),              \
    (__attribute__((address_space(3))) unsigned int*)(l), 16, 0, 0)

// ---------------------------------------------------------------------------
// Transpose + f32->bf16 convert:  src (nmat, R, C) f32  ->  dst (nmat, C, R) bf16
// ---------------------------------------------------------------------------
__global__ __launch_bounds__(256) void transpose_cvt_kernel(
    const float* __restrict__ src, unsigned short* __restrict__ dst,
    int R, int C) {
  __shared__ float t[32][33];
  const float* s = src + (size_t)blockIdx.z * R * C;
  unsigned short* d = dst + (size_t)blockIdx.z * R * C;
  int c0 = blockIdx.x * 32, r0 = blockIdx.y * 32;
  int x = threadIdx.x, y = threadIdx.y;      // 32 x 8
#pragma unroll
  for (int j = 0; j < 32; j += 8)
    t[y + j][x] = s[(size_t)(r0 + y + j) * C + (c0 + x)];
  __syncthreads();
#pragma unroll
  for (int j = 0; j < 32; j += 8)
    d[(size_t)(c0 + y + j) * R + (r0 + x)] = f2bf(t[x][y + j]);
}

// ---------------------------------------------------------------------------
// f32 -> bf16 convert (flat), vectorized: float4 in, 4x bf16 (8B) out
// ---------------------------------------------------------------------------
__global__ __launch_bounds__(256) void cvt_bf16_kernel(
    const float* __restrict__ src, unsigned short* __restrict__ dst, long n4) {
  long i = (long)blockIdx.x * 256 + threadIdx.x;
  long stride = (long)gridDim.x * 256;
  for (; i < n4; i += stride) {
    float4 v = ((const float4*)src)[i];
    uint2 o;
    o.x = (unsigned)f2bf(v.x) | ((unsigned)f2bf(v.y) << 16);
    o.y = (unsigned)f2bf(v.z) | ((unsigned)f2bf(v.w) << 16);
    ((uint2*)dst)[i] = o;
  }
}

// ---------------------------------------------------------------------------
// GEMM1 (bf16 A): H[r][f] = gelu( sum_k Xb[r][k] * W1t[e][f][k] + b1[e][f] )
//   Xb bf16 [32768][1024], W1t bf16 [E][F][D]
//   tile 128x128, BK=64, 4 waves (2x2), mfma 16x16x32 bf16
//   LDS: [row][8 chunks of 16B], chunk cc holds global chunk cc^(row&7)
// ---------------------------------------------------------------------------
__global__ __launch_bounds__(256) void gemm1_kernel(
    const unsigned short* __restrict__ Xb, const unsigned short* __restrict__ W1t,
    const float* __restrict__ b1, const int* __restrict__ eidx,
    unsigned short* __restrict__ H, int row0) {
  __shared__ __align__(16) char smem[32768];
  char* As = smem;            // 128 x 64 bf16 = 16KB
  char* Bs = smem + 16384;    // 128 x 64 bf16 = 16KB

  const int tid = threadIdx.x;
  const int lane = tid & 63;
  const int wave = tid >> 6;
  const int wr = wave >> 1, wc = wave & 1;
  const int l15 = lane & 15, lhi = lane >> 4;

  const int gr0 = row0 + blockIdx.x * 128;      // global row base (within B*S)
  const int bat = gr0 >> 12;                    // / 4096
  const int e = eidx[bat];
  const int col0 = blockIdx.y * 128;

  const unsigned short* Abase = Xb + (size_t)gr0 * D_;
  const unsigned short* Bbase = W1t + (size_t)e * F_ * D_ + (size_t)col0 * D_;

  f32x4 acc[4][4] = {};

  for (int kt = 0; kt < D_; kt += 64) {
#pragma unroll
    for (int i = 0; i < 4; ++i) {
      int cbase = i * 256 + (wave << 6);        // wave-uniform chunk base
      int c = cbase + lane;
      int r = c >> 3, cc = c & 7;
      int gc = cc ^ (r & 7);
      GLD16(Bbase + (size_t)r * D_ + kt + gc * 8, Bs + (size_t)cbase * 16);
      GLD16(Abase + (size_t)r * D_ + kt + gc * 8, As + (size_t)cbase * 16);
    }
    __syncthreads();
#pragma unroll
    for (int kk = 0; kk < 2; ++kk) {
      bf16x8 a[4], b[4];
#pragma unroll
      for (int m = 0; m < 4; ++m) {
        int r = wr * 64 + m * 16 + l15;
        int gc = kk * 4 + lhi;
        a[m] = *(const bf16x8*)(As + r * 128 + ((gc ^ (r & 7)) << 4));
      }
#pragma unroll
      for (int n = 0; n < 4; ++n) {
        int r = wc * 64 + n * 16 + l15;
        int gc = kk * 4 + lhi;
        b[n] = *(const bf16x8*)(Bs + r * 128 + ((gc ^ (r & 7)) << 4));
      }
#pragma unroll
      for (int m = 0; m < 4; ++m)
#pragma unroll
        for (int n = 0; n < 4; ++n)
          acc[m][n] = __builtin_amdgcn_mfma_f32_16x16x32_bf16(
              a[m], b[n], acc[m][n], 0, 0, 0);
    }
    __syncthreads();
  }

  // epilogue: + b1, exact gelu, bf16 store to H (chunk-local rows)
#pragma unroll
  for (int n = 0; n < 4; ++n) {
    int col = col0 + wc * 64 + n * 16 + l15;
    float bias = b1[(size_t)e * F_ + col];
#pragma unroll
    for (int m = 0; m < 4; ++m) {
      int rbase = blockIdx.x * 128 + wr * 64 + m * 16 + lhi * 4;
#pragma unroll
      for (int r = 0; r < 4; ++r) {
        float v = acc[m][n][r] + bias;
        v = 0.5f * v * (1.0f + erff(v * 0.70710678118654752f));
        H[(size_t)(rbase + r) * F_ + col] = f2bf(v);
      }
    }
  }
}

// ---------------------------------------------------------------------------
// GEMM1 fallback (f32 A, reg-staged) — used only if ws too small for Xb.
// ---------------------------------------------------------------------------
__global__ __launch_bounds__(256) void gemm1_f32_kernel(
    const float* __restrict__ X, const unsigned short* __restrict__ W1t,
    const float* __restrict__ b1, const int* __restrict__ eidx,
    unsigned short* __restrict__ H, int row0) {
  __shared__ __align__(16) char smem[32768];
  char* As = smem;
  char* Bs = smem + 16384;

  const int tid = threadIdx.x;
  const int lane = tid & 63;
  const int wave = tid >> 6;
  const int wr = wave >> 1, wc = wave & 1;
  const int l15 = lane & 15, lhi = lane >> 4;

  const int gr0 = row0 + blockIdx.x * 128;
  const int bat = gr0 >> 12;
  const int e = eidx[bat];
  const int col0 = blockIdx.y * 128;

  const float* Abase = X + (size_t)gr0 * D_;
  const unsigned short* Bbase = W1t + (size_t)e * F_ * D_ + (size_t)col0 * D_;

  f32x4 acc[4][4] = {};

  for (int kt = 0; kt < D_; kt += 64) {
#pragma unroll
    for (int i = 0; i < 4; ++i) {
      int cbase = i * 256 + (wave << 6);
      int c = cbase + lane;
      int r = c >> 3, cc = c & 7;
      int gc = cc ^ (r & 7);
      GLD16(Bbase + (size_t)r * D_ + kt + gc * 8, Bs + (size_t)cbase * 16);
    }
#pragma unroll
    for (int i = 0; i < 8; ++i) {
      int q = i * 256 + tid;
      int r = q >> 4, qc = q & 15;
      float4 v = *(const float4*)(Abase + (size_t)r * D_ + kt + qc * 4);
      unsigned lo = (unsigned)f2bf(v.x) | ((unsigned)f2bf(v.y) << 16);
      unsigned hi = (unsigned)f2bf(v.z) | ((unsigned)f2bf(v.w) << 16);
      int addr = r * 128 + (((qc >> 1) ^ (r & 7)) << 4) + (qc & 1) * 8;
      *(uint2*)(As + addr) = make_uint2(lo, hi);
    }
    __syncthreads();
#pragma unroll
    for (int kk = 0; kk < 2; ++kk) {
      bf16x8 a[4], b[4];
#pragma unroll
      for (int m = 0; m < 4; ++m) {
        int r = wr * 64 + m * 16 + l15;
        int gc = kk * 4 + lhi;
        a[m] = *(const bf16x8*)(As + r * 128 + ((gc ^ (r & 7)) << 4));
      }
#pragma unroll
      for (int n = 0; n < 4; ++n) {
        int r = wc * 64 + n * 16 + l15;
        int gc = kk * 4 + lhi;
        b[n] = *(const bf16x8*)(Bs + r * 128 + ((gc ^ (r & 7)) << 4));
      }
#pragma unroll
      for (int m = 0; m < 4; ++m)
#pragma unroll
        for (int n = 0; n < 4; ++n)
          acc[m][n] = __builtin_amdgcn_mfma_f32_16x16x32_bf16(
              a[m], b[n], acc[m][n], 0, 0, 0);
    }
    __syncthreads();
  }

#pragma unroll
  for (int n = 0; n < 4; ++n) {
    int col = col0 + wc * 64 + n * 16 + l15;
    float bias = b1[(size_t)e * F_ + col];
#pragma unroll
    for (int m = 0; m < 4; ++m) {
      int rbase = blockIdx.x * 128 + wr * 64 + m * 16 + lhi * 4;
#pragma unroll
      for (int r = 0; r < 4; ++r) {
        float v = acc[m][n][r] + bias;
        v = 0.5f * v * (1.0f + erff(v * 0.70710678118654752f));
        H[(size_t)(rbase + r) * F_ + col] = f2bf(v);
      }
    }
  }
}

// ---------------------------------------------------------------------------
// GEMM2: Y[r][d] = ( sum_f H[r][f] * W2t[e][d][f] + b2[e][d] ) * w[b]  (f32 out)
//   H bf16 [chunk][F], W2t bf16 [E][D][F]
// ---------------------------------------------------------------------------
__global__ __launch_bounds__(256) void gemm2_kernel(
    const unsigned short* __restrict__ H, const unsigned short* __restrict__ W2t,
    const float* __restrict__ b2, const int* __restrict__ eidx,
    const float* __restrict__ ew, float* __restrict__ Y, int row0) {
  __shared__ __align__(16) char smem[32768];
  char* As = smem;
  char* Bs = smem + 16384;

  const int tid = threadIdx.x;
  const int lane = tid & 63;
  const int wave = tid >> 6;
  const int wr = wave >> 1, wc = wave & 1;
  const int l15 = lane & 15, lhi = lane >> 4;

  const int gr0 = row0 + blockIdx.x * 128;
  const int bat = gr0 >> 12;
  const int e = eidx[bat];
  const float scale = ew[bat];
  const int col0 = blockIdx.y * 128;

  const unsigned short* Abase = H + (size_t)(blockIdx.x * 128) * F_;
  const unsigned short* Bbase = W2t + (size_t)e * D_ * F_ + (size_t)col0 * F_;

  f32x4 acc[4][4] = {};

  for (int kt = 0; kt < F_; kt += 64) {
#pragma unroll
    for (int i = 0; i < 4; ++i) {
      int cbase = i * 256 + (wave << 6);
      int c = cbase + lane;
      int r = c >> 3, cc = c & 7;
      int gc = cc ^ (r & 7);
      GLD16(Bbase + (size_t)r * F_ + kt + gc * 8, Bs + (size_t)cbase * 16);
      GLD16(Abase + (size_t)r * F_ + kt + gc * 8, As + (size_t)cbase * 16);
    }
    __syncthreads();
#pragma unroll
    for (int kk = 0; kk < 2; ++kk) {
      bf16x8 a[4], b[4];
#pragma unroll
      for (int m = 0; m < 4; ++m) {
        int r = wr * 64 + m * 16 + l15;
        int gc = kk * 4 + lhi;
        a[m] = *(const bf16x8*)(As + r * 128 + ((gc ^ (r & 7)) << 4));
      }
#pragma unroll
      for (int n = 0; n < 4; ++n) {
        int r = wc * 64 + n * 16 + l15;
        int gc = kk * 4 + lhi;
        b[n] = *(const bf16x8*)(Bs + r * 128 + ((gc ^ (r & 7)) << 4));
      }
#pragma unroll
      for (int m = 0; m < 4; ++m)
#pragma unroll
        for (int n = 0; n < 4; ++n)
          acc[m][n] = __builtin_amdgcn_mfma_f32_16x16x32_bf16(
              a[m], b[n], acc[m][n], 0, 0, 0);
    }
    __syncthreads();
  }

#pragma unroll
  for (int n = 0; n < 4; ++n) {
    int col = col0 + wc * 64 + n * 16 + l15;
    float bias = b2[(size_t)e * D_ + col];
#pragma unroll
    for (int m = 0; m < 4; ++m) {
      int grbase = gr0 + wr * 64 + m * 16 + lhi * 4;
#pragma unroll
      for (int r = 0; r < 4; ++r)
        Y[(size_t)(grbase + r) * D_ + col] = (acc[m][n][r] + bias) * scale;
    }
  }
}

// ---------------------------------------------------------------------------
extern "C" void kernel_launch(void* const* d_in, const int* in_sizes, int n_in,
                              void* d_out, int out_size, void* d_ws,
                              size_t ws_size, hipStream_t stream) {
  const float* x = (const float*)d_in[0];
  const float* ew = (const float*)d_in[1];
  const float* W1 = (const float*)d_in[2];
  const float* b1 = (const float*)d_in[3];
  const float* W2 = (const float*)d_in[4];
  const float* b2 = (const float*)d_in[5];
  const int* eidx = (const int*)d_in[6];
  float* out = (float*)d_out;

  char* ws = (char*)d_ws;
  const size_t WT = (size_t)E_ * F_ * D_ * 2;       // 64 MiB per transposed weight
  const size_t XB = (size_t)B_ * S_ * D_ * 2;       // 64 MiB bf16 x
  unsigned short* w1t = (unsigned short*)ws;
  unsigned short* w2t = (unsigned short*)(ws + WT);

  // Pre-transpose + bf16-convert weights: W1 (E,D,F)->(E,F,D), W2 (E,F,D)->(E,D,F)
  transpose_cvt_kernel<<<dim3(F_ / 32, D_ / 32, E_), dim3(32, 8), 0, stream>>>(
      W1, w1t, D_, F_);
  transpose_cvt_kernel<<<dim3(D_ / 32, F_ / 32, E_), dim3(32, 8), 0, stream>>>(
      W2, w2t, F_, D_);

  const long total_rows = (long)B_ * S_;  // 32768
  const long MIN_H = 128;

  // Preferred layout: [w1t][w2t][xbf][hbuf...]
  long hcap_pref = ((long)ws_size - (long)(2 * WT + XB)) / ((long)F_ * 2);
  bool use_xb = hcap_pref >= MIN_H;

  if (use_xb) {
    unsigned short* xbf = (unsigned short*)(ws + 2 * WT);
    unsigned short* hbuf = (unsigned short*)(ws + 2 * WT + XB);
    cvt_bf16_kernel<<<2048, 256, 0, stream>>>(x, xbf,
                                              (long)B_ * S_ * D_ / 4);
    long chunk = (hcap_pref / 128) * 128;
    if (chunk > total_rows) chunk = total_rows;
    for (long r0 = 0; r0 < total_rows; r0 += chunk) {
      long nr = total_rows - r0;
      if (nr > chunk) nr = chunk;
      gemm1_kernel<<<dim3(nr / 128, F_ / 128), 256, 0, stream>>>(
          xbf, w1t, b1, eidx, hbuf, (int)r0);
      gemm2_kernel<<<dim3(nr / 128, D_ / 128), 256, 0, stream>>>(
          hbuf, w2t, b2, eidx, ew, out, (int)r0);
    }
  } else {
    unsigned short* hbuf = (unsigned short*)(ws + 2 * WT);
    long hcap = ((long)ws_size - (long)(2 * WT)) / ((long)F_ * 2);
    long chunk = (hcap / 128) * 128;
    if (chunk > total_rows) chunk = total_rows;
    if (chunk < 128) chunk = 128;
    for (long r0 = 0; r0 < total_rows; r0 += chunk) {
      long nr = total_rows - r0;
      if (nr > chunk) nr = chunk;
      gemm1_f32_kernel<<<dim3(nr / 128, F_ / 128), 256, 0, stream>>>(
          x, w1t, b1, eidx, hbuf, (int)r0);
      gemm2_kernel<<<dim3(nr / 128, D_ / 128), 256, 0, stream>>>(
          hbuf, w2t, b2, eidx, ew, out, (int)r0);
    }
  }
}

// Round 3
// 719.813 us; speedup vs baseline: 1.8177x; 1.5981x over previous
//
#include <hip/hip_runtime.h>
#include <hip/hip_bf16.h>

// MoE expert MLP: y[b] = (gelu(x[b] @ W1[e] + b1[e]) @ W2[e] + b2[e]) * w[b]
// B=8, S=4096, D=1024, F=4096, E=8. f32 in/out; bf16 MFMA, 256^2 8-phase.

#define B_ 8
#define S_ 4096
#define D_ 1024
#define F_ 4096
#define E_ 8

typedef __bf16 bf16x8 __attribute__((ext_vector_type(8)));
typedef float f32x4 __attribute__((ext_vector_type(4)));

__device__ __forceinline__ unsigned short f2bf(float f) {
  unsigned u = __float_as_uint(f);
  u += 0x7FFFu + ((u >> 16) & 1u);   // round-to-nearest-even
  return (unsigned short)(u >> 16);
}

#define GLD16(g, l) __builtin_amdgcn_global_load_lds(                         \
    (const __attribute__((address_space(1))) unsigned int*)(g),              \
    (__attribute__((address_space(3))) unsigned int*)(l), 16, 0, 0)

// ---------------------------------------------------------------------------
// Transpose + f32->bf16:  src (nmat, R, C) f32  ->  dst (nmat, C, R) bf16
// ---------------------------------------------------------------------------
__global__ __launch_bounds__(256) void transpose_cvt_kernel(
    const float* __restrict__ src, unsigned short* __restrict__ dst,
    int R, int C) {
  __shared__ float t[32][33];
  const float* s = src + (size_t)blockIdx.z * R * C;
  unsigned short* d = dst + (size_t)blockIdx.z * R * C;
  int c0 = blockIdx.x * 32, r0 = blockIdx.y * 32;
  int x = threadIdx.x, y = threadIdx.y;      // 32 x 8
#pragma unroll
  for (int j = 0; j < 32; j += 8)
    t[y + j][x] = s[(size_t)(r0 + y + j) * C + (c0 + x)];
  __syncthreads();
#pragma unroll
  for (int j = 0; j < 32; j += 8)
    d[(size_t)(c0 + y + j) * R + (r0 + x)] = f2bf(t[x][y + j]);
}

// ---------------------------------------------------------------------------
// f32 -> bf16 flat convert, vectorized
// ---------------------------------------------------------------------------
__global__ __launch_bounds__(256) void cvt_bf16_kernel(
    const float* __restrict__ src, unsigned short* __restrict__ dst, long n4) {
  long i = (long)blockIdx.x * 256 + threadIdx.x;
  long stride = (long)gridDim.x * 256;
  for (; i < n4; i += stride) {
    float4 v = ((const float4*)src)[i];
    uint2 o;
    o.x = (unsigned)f2bf(v.x) | ((unsigned)f2bf(v.y) << 16);
    o.y = (unsigned)f2bf(v.z) | ((unsigned)f2bf(v.w) << 16);
    ((uint2*)dst)[i] = o;
  }
}

// ---------------------------------------------------------------------------
// 256x256-tile 8-phase GEMM (HK-style schedule in plain HIP).
//   C[row][col] = A[row][k] * Bw[e][col][k]  (+bias, optional gelu/scale)
//   8 waves (2M x 4N), per-wave 128x64 output, BK=64, mfma 16x16x32 bf16.
//   LDS 128 KiB: buf{0,1} x { A[2 halves 128x64] , B[2 halves 128x64] },
//   16B-chunk XOR swizzle: chunk cc of row r holds global k-chunk cc^(r&7).
//   Staging issue order per tile t: ph1 Ah1(t+1), ph2 Ah0(t+2), ph3 Bh0(t+2),
//   ph4 Bh1(t+2); vmcnt(6) only at ph4 (3 halves stay in flight).
//   Region-retirement: Ah0,Bh0 dead after ph1; Bh1 after ph2; Ah1 after ph3.
// ---------------------------------------------------------------------------

#define STAGE(cur, op, h, tk, base)                                           \
  {                                                                           \
    const unsigned short* g0_ = (base) + (size_t)((h) * 128 + sr) * LDK +     \
                                (tk) * 64 + sgc * 8;                          \
    GLD16(g0_, smem + (cur) * 65536 + (op) * 32768 + (h) * 16384 +            \
                   wave * 1024);                                              \
    GLD16(g0_ + (size_t)64 * LDK,                                             \
          smem + (cur) * 65536 + (op) * 32768 + (h) * 16384 + 8192 +          \
              wave * 1024);                                                   \
  }

#define LDA_HALF(cur, H)                                                      \
  _Pragma("unroll") for (int m = 0; m < 4; ++m) {                             \
    const char* p_ = smem + (cur) * 65536 + (H) * 16384 +                     \
                     (wr * 64 + m * 16 + l15) * 128;                          \
    aM[m][0] = *(const bf16x8*)(p_ + ca0);                                    \
    aM[m][1] = *(const bf16x8*)(p_ + ca1);                                    \
  }

#define LDB_Q(cur, Q, breg)                                                   \
  _Pragma("unroll") for (int n = 0; n < 2; ++n) {                             \
    const char* p_ = smem + (cur) * 65536 + 32768 + (Q) * 16384 +             \
                     (wc * 32 + n * 16 + l15) * 128;                          \
    breg[n][0] = *(const bf16x8*)(p_ + ca0);                                  \
    breg[n][1] = *(const bf16x8*)(p_ + ca1);                                  \
  }

#define MMA_Q(MB, breg, NB)                                                   \
  _Pragma("unroll") for (int ks = 0; ks < 2; ++ks)                            \
      _Pragma("unroll") for (int m = 0; m < 4; ++m)                           \
          _Pragma("unroll") for (int n = 0; n < 2; ++n)                       \
              acc[(MB) + m][(NB) + n] =                                       \
      __builtin_amdgcn_mfma_f32_16x16x32_bf16(                                \
          aM[m][ks], breg[n][ks], acc[(MB) + m][(NB) + n], 0, 0, 0);

#define PH_MID                                                                \
  __builtin_amdgcn_s_barrier();                                               \
  asm volatile("s_waitcnt lgkmcnt(0)" ::: "memory");                          \
  __builtin_amdgcn_sched_barrier(0);                                          \
  __builtin_amdgcn_s_setprio(1);

#define PH_END                                                                \
  __builtin_amdgcn_s_setprio(0);                                              \
  __builtin_amdgcn_s_barrier();

// MODE: 2 = full staging, 1 = tail-1 (stage Ah1 only, drain), 0 = last tile
#define TILE(cur, t, MODE)                                                    \
  LDA_HALF(cur, 0);                                                           \
  LDB_Q(cur, 0, bq0);                                                         \
  if ((MODE) >= 1) STAGE((cur) ^ 1, 0, 1, (t) + 1, Abase);                    \
  PH_MID; MMA_Q(0, bq0, 0); PH_END;                                           \
  LDB_Q(cur, 1, bq1);                                                         \
  if ((MODE) == 2) STAGE(cur, 0, 0, (t) + 2, Abase);                          \
  PH_MID; MMA_Q(0, bq1, 2); PH_END;                                           \
  LDA_HALF(cur, 1);                                                           \
  if ((MODE) == 2) STAGE(cur, 1, 0, (t) + 2, Bbase);                          \
  PH_MID; MMA_Q(4, bq0, 0); PH_END;                                           \
  if ((MODE) == 2) STAGE(cur, 1, 1, (t) + 2, Bbase);                          \
  __builtin_amdgcn_s_barrier();                                               \
  __builtin_amdgcn_s_setprio(1);                                              \
  MMA_Q(4, bq1, 2);                                                           \
  __builtin_amdgcn_s_setprio(0);                                              \
  if ((MODE) == 2) asm volatile("s_waitcnt vmcnt(6)" ::: "memory");           \
  if ((MODE) == 1) asm volatile("s_waitcnt vmcnt(0)" ::: "memory");           \
  __builtin_amdgcn_s_barrier();

template <int NT, int LDK, int NCOL, bool GELU>
__global__ __launch_bounds__(512, 2) void gemm8p_kernel(
    const unsigned short* __restrict__ A,   // [rows][LDK] bf16 (chunk-local)
    const unsigned short* __restrict__ Bw,  // [E][NCOL][LDK] bf16
    const float* __restrict__ bias,         // [E][NCOL]
    const int* __restrict__ eidx, const float* __restrict__ ew,
    void* __restrict__ Out, int grow0, int nbm) {
  extern __shared__ __align__(16) char smem[];

  const int tid = threadIdx.x;
  const int lane = tid & 63;
  const int wave = tid >> 6;
  const int wr = wave >> 2;         // 0..1 (M)
  const int wc = wave & 3;          // 0..3 (N)
  const int l15 = lane & 15, lhi = lane >> 4;

  const int nwg = nbm * (NCOL / 256);
  int wg = blockIdx.x;
  if ((nwg & 7) == 0) wg = (wg & 7) * (nwg >> 3) + (wg >> 3);  // XCD swizzle
  const int bm = wg % nbm, bn = wg / nbm;

  const int bat = (grow0 + bm * 256) >> 12;
  const int e = eidx[bat];

  const unsigned short* Abase = A + (size_t)bm * 256 * LDK;
  const unsigned short* Bbase =
      Bw + (size_t)e * (F_ * D_) + (size_t)bn * 256 * LDK;

  // staging per-thread constants (swizzled source)
  const int sr = tid >> 3;                  // 0..63 (row within 64-row slab)
  const int sgc = (tid & 7) ^ (sr & 7);     // global 16B chunk for lds chunk
  // ds_read per-thread swizzled chunk offsets (row&7 == l15&7 always)
  const int ca0 = ((lhi ^ (l15 & 7)) << 4);
  const int ca1 = (((4 + lhi) ^ (l15 & 7)) << 4);

  f32x4 acc[8][4] = {};
  bf16x8 aM[4][2], bq0[2][2], bq1[2][2];

  // prologue: tile0 all 4 halves, tile1 first 3 (Ah0,Bh0,Bh1)
  STAGE(0, 0, 0, 0, Abase);
  STAGE(0, 1, 0, 0, Bbase);
  STAGE(0, 1, 1, 0, Bbase);
  STAGE(0, 0, 1, 0, Abase);
  STAGE(1, 0, 0, 1, Abase);
  STAGE(1, 1, 0, 1, Bbase);
  STAGE(1, 1, 1, 1, Bbase);
  asm volatile("s_waitcnt vmcnt(6)" ::: "memory");
  __builtin_amdgcn_s_barrier();

#pragma unroll 1
  for (int t = 0; t < NT - 2; t += 2) {
    TILE(0, t, 2);
    TILE(1, t + 1, 2);
  }
  TILE(0, NT - 2, 1);
  TILE(1, NT - 1, 0);

  // epilogue
  const float scale = GELU ? 1.0f : ew[bat];
#pragma unroll
  for (int n = 0; n < 4; ++n) {
    const int tcol =
        (n < 2 ? wc * 32 + n * 16 : 128 + wc * 32 + (n - 2) * 16) + l15;
    const int col = bn * 256 + tcol;
    const float bv = bias[(size_t)e * NCOL + col];
#pragma unroll
    for (int m = 0; m < 8; ++m) {
      const int trow =
          (m < 4 ? wr * 64 + m * 16 : 128 + wr * 64 + (m - 4) * 16) + lhi * 4;
      const size_t rowb = (size_t)bm * 256 + trow;
#pragma unroll
      for (int r = 0; r < 4; ++r) {
        float v = acc[m][n][r] + bv;
        if (GELU) {
          // tanh-form gelu: v * sigmoid(2 * 0.79788456*(v + 0.044715 v^3))
          float zz = v * (0.79788456080286536f + 0.0356774081f * v * v);
          float g = v / (1.0f + __expf(-2.0f * zz));
          ((unsigned short*)Out)[(rowb + r) * NCOL + col] = f2bf(g);
        } else {
          ((float*)Out)[(rowb + r) * NCOL + col] = v * scale;
        }
      }
    }
  }
}

// ---------------------------------------------------------------------------
extern "C" void kernel_launch(void* const* d_in, const int* in_sizes, int n_in,
                              void* d_out, int out_size, void* d_ws,
                              size_t ws_size, hipStream_t stream) {
  const float* x = (const float*)d_in[0];
  const float* ew = (const float*)d_in[1];
  const float* W1 = (const float*)d_in[2];
  const float* b1 = (const float*)d_in[3];
  const float* W2 = (const float*)d_in[4];
  const float* b2 = (const float*)d_in[5];
  const int* eidx = (const int*)d_in[6];
  float* out = (float*)d_out;

  char* ws = (char*)d_ws;
  const size_t WT = (size_t)E_ * F_ * D_ * 2;  // 64 MiB per transposed weight
  const size_t XB = (size_t)B_ * S_ * D_ * 2;  // 64 MiB bf16 x
  unsigned short* w1t = (unsigned short*)ws;
  unsigned short* w2t = (unsigned short*)(ws + WT);

  auto g1 = gemm8p_kernel<16, D_, F_, true>;
  auto g2 = gemm8p_kernel<64, F_, D_, false>;
  hipFuncSetAttribute((const void*)g1,
                      hipFuncAttributeMaxDynamicSharedMemorySize, 131072);
  hipFuncSetAttribute((const void*)g2,
                      hipFuncAttributeMaxDynamicSharedMemorySize, 131072);

  // weights: W1 (E,D,F)->(E,F,D), W2 (E,F,D)->(E,D,F), bf16
  transpose_cvt_kernel<<<dim3(F_ / 32, D_ / 32, E_), dim3(32, 8), 0, stream>>>(
      W1, w1t, D_, F_);
  transpose_cvt_kernel<<<dim3(D_ / 32, F_ / 32, E_), dim3(32, 8), 0, stream>>>(
      W2, w2t, F_, D_);

  const long total_rows = (long)B_ * S_;  // 32768
  long hcap = ((long)ws_size - (long)(2 * WT + XB)) / ((long)F_ * 2);

  if (hcap >= total_rows) {
    // full: [w1t][w2t][xbf][hbuf]
    unsigned short* xbf = (unsigned short*)(ws + 2 * WT);
    unsigned short* hbuf = (unsigned short*)(ws + 2 * WT + XB);
    cvt_bf16_kernel<<<2048, 256, 0, stream>>>(x, xbf, (long)B_ * S_ * D_ / 4);
    int nbm = (int)(total_rows / 256);
    g1<<<dim3(nbm * (F_ / 256)), 512, 131072, stream>>>(
        xbf, w1t, b1, eidx, ew, hbuf, 0, nbm);
    g2<<<dim3(nbm * (D_ / 256)), 512, 131072, stream>>>(
        hbuf, w2t, b2, eidx, ew, out, 0, nbm);
  } else {
    // chunked: [w1t][w2t][xbf_chunk][h_chunk]
    long cap = ((long)ws_size - (long)(2 * WT)) / ((long)(D_ + F_) * 2);
    long chunk = (cap / 256) * 256;
    if (chunk > total_rows) chunk = total_rows;
    if (chunk < 256) chunk = 256;
    unsigned short* xbf = (unsigned short*)(ws + 2 * WT);
    unsigned short* hbuf = xbf + (size_t)chunk * D_;
    for (long r0 = 0; r0 < total_rows; r0 += chunk) {
      long nr = total_rows - r0;
      if (nr > chunk) nr = chunk;
      cvt_bf16_kernel<<<512, 256, 0, stream>>>(x + r0 * D_, xbf, nr * D_ / 4);
      int nbm = (int)(nr / 256);
      g1<<<dim3(nbm * (F_ / 256)), 512, 131072, stream>>>(
          xbf, w1t, b1, eidx, ew, hbuf, (int)r0, nbm);
      g2<<<dim3(nbm * (D_ / 256)), 512, 131072, stream>>>(
          hbuf, w2t, b2, eidx, ew, out + r0 * D_, (int)r0, nbm);
    }
  }
}

// Round 4
// 716.413 us; speedup vs baseline: 1.8263x; 1.0047x over previous
//
#include <hip/hip_runtime.h>
#include <hip/hip_bf16.h>

// MoE expert MLP: y[b] = (gelu(x[b] @ W1[e] + b1[e]) @ W2[e] + b2[e]) * w[b]
// B=8, S=4096, D=1024, F=4096, E=8. f32 in/out; bf16 MFMA, 256^2 8-phase.

#define B_ 8
#define S_ 4096
#define D_ 1024
#define F_ 4096
#define E_ 8

typedef __bf16 bf16x8 __attribute__((ext_vector_type(8)));
typedef float f32x4 __attribute__((ext_vector_type(4)));

__device__ __forceinline__ unsigned short f2bf(float f) {
  unsigned u = __float_as_uint(f);
  u += 0x7FFFu + ((u >> 16) & 1u);   // round-to-nearest-even
  return (unsigned short)(u >> 16);
}

#define GLD16(g, l) __builtin_amdgcn_global_load_lds(                         \
    (const __attribute__((address_space(1))) unsigned int*)(g),              \
    (__attribute__((address_space(3))) unsigned int*)(l), 16, 0, 0)

// ---------------------------------------------------------------------------
// Transpose + f32->bf16:  src (nmat, R, C) f32  ->  dst (nmat, C, R) bf16
// ---------------------------------------------------------------------------
__global__ __launch_bounds__(256) void transpose_cvt_kernel(
    const float* __restrict__ src, unsigned short* __restrict__ dst,
    int R, int C) {
  __shared__ float t[32][33];
  const float* s = src + (size_t)blockIdx.z * R * C;
  unsigned short* d = dst + (size_t)blockIdx.z * R * C;
  int c0 = blockIdx.x * 32, r0 = blockIdx.y * 32;
  int x = threadIdx.x, y = threadIdx.y;      // 32 x 8
#pragma unroll
  for (int j = 0; j < 32; j += 8)
    t[y + j][x] = s[(size_t)(r0 + y + j) * C + (c0 + x)];
  __syncthreads();
#pragma unroll
  for (int j = 0; j < 32; j += 8)
    d[(size_t)(c0 + y + j) * R + (r0 + x)] = f2bf(t[x][y + j]);
}

// ---------------------------------------------------------------------------
// f32 -> bf16 flat convert, vectorized
// ---------------------------------------------------------------------------
__global__ __launch_bounds__(256) void cvt_bf16_kernel(
    const float* __restrict__ src, unsigned short* __restrict__ dst, long n4) {
  long i = (long)blockIdx.x * 256 + threadIdx.x;
  long stride = (long)gridDim.x * 256;
  for (; i < n4; i += stride) {
    float4 v = ((const float4*)src)[i];
    uint2 o;
    o.x = (unsigned)f2bf(v.x) | ((unsigned)f2bf(v.y) << 16);
    o.y = (unsigned)f2bf(v.z) | ((unsigned)f2bf(v.w) << 16);
    ((uint2*)dst)[i] = o;
  }
}

// ---------------------------------------------------------------------------
// 256x256-tile 8-phase GEMM (HK-style schedule in plain HIP).
//   C[row][col] = A[row][k] * Bw[e][col][k]  (+bias, optional gelu/scale)
//   8 waves (2M x 4N), per-wave 128x64 output, BK=64, mfma 16x16x32 bf16.
//   LDS 128 KiB: buf{0,1} x { A[2 halves 128x64] , B[2 halves 128x64] },
//   16B-chunk XOR swizzle: chunk cc of row r holds global k-chunk cc^(r&7).
//   Staging issue order per tile t: ph1 Ah1(t+1), ph2 Ah0(t+2), ph3 Bh0(t+2),
//   ph4 Bh1(t+2); vmcnt(6) only at ph4 (3 halves stay in flight).
//   NOTE (R4): no explicit lgkmcnt(0) before MFMA clusters — compiler emits
//   fine-grained per-MFMA lgkmcnt(N), letting ds_read drain overlap MFMA
//   within the phase. Every phase's reads are consumed by that phase's MFMA
//   cluster, so all reads complete before PH_END's barrier (staging safety).
// ---------------------------------------------------------------------------

#define STAGE(cur, op, h, tk, base)                                           \
  {                                                                           \
    const unsigned short* g0_ = (base) + (size_t)((h) * 128 + sr) * LDK +     \
                                (tk) * 64 + sgc * 8;                          \
    GLD16(g0_, smem + (cur) * 65536 + (op) * 32768 + (h) * 16384 +            \
                   wave * 1024);                                              \
    GLD16(g0_ + (size_t)64 * LDK,                                             \
          smem + (cur) * 65536 + (op) * 32768 + (h) * 16384 + 8192 +          \
              wave * 1024);                                                   \
  }

#define LDA_HALF(cur, H)                                                      \
  _Pragma("unroll") for (int m = 0; m < 4; ++m) {                             \
    const char* p_ = smem + (cur) * 65536 + (H) * 16384 +                     \
                     (wr * 64 + m * 16 + l15) * 128;                          \
    aM[m][0] = *(const bf16x8*)(p_ + ca0);                                    \
    aM[m][1] = *(const bf16x8*)(p_ + ca1);                                    \
  }

#define LDB_Q(cur, Q, breg)                                                   \
  _Pragma("unroll") for (int n = 0; n < 2; ++n) {                             \
    const char* p_ = smem + (cur) * 65536 + 32768 + (Q) * 16384 +             \
                     (wc * 32 + n * 16 + l15) * 128;                          \
    breg[n][0] = *(const bf16x8*)(p_ + ca0);                                  \
    breg[n][1] = *(const bf16x8*)(p_ + ca1);                                  \
  }

#define MMA_Q(MB, breg, NB)                                                   \
  _Pragma("unroll") for (int ks = 0; ks < 2; ++ks)                            \
      _Pragma("unroll") for (int m = 0; m < 4; ++m)                           \
          _Pragma("unroll") for (int n = 0; n < 2; ++n)                       \
              acc[(MB) + m][(NB) + n] =                                       \
      __builtin_amdgcn_mfma_f32_16x16x32_bf16(                                \
          aM[m][ks], breg[n][ks], acc[(MB) + m][(NB) + n], 0, 0, 0);

#define PH_MID                                                                \
  __builtin_amdgcn_s_barrier();                                               \
  __builtin_amdgcn_s_setprio(1);

#define PH_END                                                                \
  __builtin_amdgcn_s_setprio(0);                                              \
  __builtin_amdgcn_sched_barrier(0);                                          \
  __builtin_amdgcn_s_barrier();

// MODE: 2 = full staging, 1 = tail-1 (stage Ah1 only, drain), 0 = last tile
#define TILE(cur, t, MODE)                                                    \
  LDA_HALF(cur, 0);                                                           \
  LDB_Q(cur, 0, bq0);                                                         \
  if ((MODE) >= 1) STAGE((cur) ^ 1, 0, 1, (t) + 1, Abase);                    \
  PH_MID; MMA_Q(0, bq0, 0); PH_END;                                           \
  LDB_Q(cur, 1, bq1);                                                         \
  if ((MODE) == 2) STAGE(cur, 0, 0, (t) + 2, Abase);                          \
  PH_MID; MMA_Q(0, bq1, 2); PH_END;                                           \
  LDA_HALF(cur, 1);                                                           \
  if ((MODE) == 2) STAGE(cur, 1, 0, (t) + 2, Bbase);                          \
  PH_MID; MMA_Q(4, bq0, 0); PH_END;                                           \
  if ((MODE) == 2) STAGE(cur, 1, 1, (t) + 2, Bbase);                          \
  __builtin_amdgcn_s_barrier();                                               \
  __builtin_amdgcn_s_setprio(1);                                              \
  MMA_Q(4, bq1, 2);                                                           \
  __builtin_amdgcn_s_setprio(0);                                              \
  __builtin_amdgcn_sched_barrier(0);                                          \
  if ((MODE) == 2) asm volatile("s_waitcnt vmcnt(6)" ::: "memory");           \
  if ((MODE) == 1) asm volatile("s_waitcnt vmcnt(0)" ::: "memory");           \
  __builtin_amdgcn_s_barrier();

template <int NT, int LDK, int NCOL, bool GELU>
__global__ __launch_bounds__(512, 2) void gemm8p_kernel(
    const unsigned short* __restrict__ A,   // [rows][LDK] bf16 (chunk-local)
    const unsigned short* __restrict__ Bw,  // [E][NCOL][LDK] bf16
    const float* __restrict__ bias,         // [E][NCOL]
    const int* __restrict__ eidx, const float* __restrict__ ew,
    void* __restrict__ Out, int grow0, int nbm) {
  extern __shared__ __align__(16) char smem[];

  const int tid = threadIdx.x;
  const int lane = tid & 63;
  const int wave = tid >> 6;
  const int wr = wave >> 2;         // 0..1 (M)
  const int wc = wave & 3;          // 0..3 (N)
  const int l15 = lane & 15, lhi = lane >> 4;

  const int nwg = nbm * (NCOL / 256);
  int wg = blockIdx.x;
  if ((nwg & 7) == 0) wg = (wg & 7) * (nwg >> 3) + (wg >> 3);  // XCD swizzle
  const int bm = wg % nbm, bn = wg / nbm;

  const int bat = (grow0 + bm * 256) >> 12;
  const int e = eidx[bat];

  const unsigned short* Abase = A + (size_t)bm * 256 * LDK;
  const unsigned short* Bbase =
      Bw + (size_t)e * (F_ * D_) + (size_t)bn * 256 * LDK;

  // staging per-thread constants (swizzled source)
  const int sr = tid >> 3;                  // 0..63 (row within 64-row slab)
  const int sgc = (tid & 7) ^ (sr & 7);     // global 16B chunk for lds chunk
  // ds_read per-thread swizzled chunk offsets (row&7 == l15&7 always)
  const int ca0 = ((lhi ^ (l15 & 7)) << 4);
  const int ca1 = (((4 + lhi) ^ (l15 & 7)) << 4);

  f32x4 acc[8][4] = {};
  bf16x8 aM[4][2], bq0[2][2], bq1[2][2];

  // prologue: tile0 all 4 halves, tile1 first 3 (Ah0,Bh0,Bh1)
  STAGE(0, 0, 0, 0, Abase);
  STAGE(0, 1, 0, 0, Bbase);
  STAGE(0, 1, 1, 0, Bbase);
  STAGE(0, 0, 1, 0, Abase);
  STAGE(1, 0, 0, 1, Abase);
  STAGE(1, 1, 0, 1, Bbase);
  STAGE(1, 1, 1, 1, Bbase);
  asm volatile("s_waitcnt vmcnt(6)" ::: "memory");
  __builtin_amdgcn_s_barrier();

#pragma unroll 1
  for (int t = 0; t < NT - 2; t += 2) {
    TILE(0, t, 2);
    TILE(1, t + 1, 2);
  }
  TILE(0, NT - 2, 1);
  TILE(1, NT - 1, 0);

  // epilogue
  const float scale = GELU ? 1.0f : ew[bat];
#pragma unroll
  for (int n = 0; n < 4; ++n) {
    const int tcol =
        (n < 2 ? wc * 32 + n * 16 : 128 + wc * 32 + (n - 2) * 16) + l15;
    const int col = bn * 256 + tcol;
    const float bv = bias[(size_t)e * NCOL + col];
#pragma unroll
    for (int m = 0; m < 8; ++m) {
      const int trow =
          (m < 4 ? wr * 64 + m * 16 : 128 + wr * 64 + (m - 4) * 16) + lhi * 4;
      const size_t rowb = (size_t)bm * 256 + trow;
#pragma unroll
      for (int r = 0; r < 4; ++r) {
        float v = acc[m][n][r] + bv;
        if (GELU) {
          // tanh-form gelu: v * sigmoid(2 * 0.79788456*(v + 0.044715 v^3))
          float zz = v * (0.79788456080286536f + 0.0356774081f * v * v);
          float g = v / (1.0f + __expf(-2.0f * zz));
          ((unsigned short*)Out)[(rowb + r) * NCOL + col] = f2bf(g);
        } else {
          ((float*)Out)[(rowb + r) * NCOL + col] = v * scale;
        }
      }
    }
  }
}

// ---------------------------------------------------------------------------
extern "C" void kernel_launch(void* const* d_in, const int* in_sizes, int n_in,
                              void* d_out, int out_size, void* d_ws,
                              size_t ws_size, hipStream_t stream) {
  const float* x = (const float*)d_in[0];
  const float* ew = (const float*)d_in[1];
  const float* W1 = (const float*)d_in[2];
  const float* b1 = (const float*)d_in[3];
  const float* W2 = (const float*)d_in[4];
  const float* b2 = (const float*)d_in[5];
  const int* eidx = (const int*)d_in[6];
  float* out = (float*)d_out;

  char* ws = (char*)d_ws;
  const size_t WT = (size_t)E_ * F_ * D_ * 2;  // 64 MiB per transposed weight
  const size_t XB = (size_t)B_ * S_ * D_ * 2;  // 64 MiB bf16 x
  unsigned short* w1t = (unsigned short*)ws;
  unsigned short* w2t = (unsigned short*)(ws + WT);

  auto g1 = gemm8p_kernel<16, D_, F_, true>;
  auto g2 = gemm8p_kernel<64, F_, D_, false>;
  hipFuncSetAttribute((const void*)g1,
                      hipFuncAttributeMaxDynamicSharedMemorySize, 131072);
  hipFuncSetAttribute((const void*)g2,
                      hipFuncAttributeMaxDynamicSharedMemorySize, 131072);

  // weights: W1 (E,D,F)->(E,F,D), W2 (E,F,D)->(E,D,F), bf16
  transpose_cvt_kernel<<<dim3(F_ / 32, D_ / 32, E_), dim3(32, 8), 0, stream>>>(
      W1, w1t, D_, F_);
  transpose_cvt_kernel<<<dim3(D_ / 32, F_ / 32, E_), dim3(32, 8), 0, stream>>>(
      W2, w2t, F_, D_);

  const long total_rows = (long)B_ * S_;  // 32768
  long hcap = ((long)ws_size - (long)(2 * WT + XB)) / ((long)F_ * 2);

  if (hcap >= total_rows) {
    // full: [w1t][w2t][xbf][hbuf]
    unsigned short* xbf = (unsigned short*)(ws + 2 * WT);
    unsigned short* hbuf = (unsigned short*)(ws + 2 * WT + XB);
    cvt_bf16_kernel<<<2048, 256, 0, stream>>>(x, xbf, (long)B_ * S_ * D_ / 4);
    int nbm = (int)(total_rows / 256);
    g1<<<dim3(nbm * (F_ / 256)), 512, 131072, stream>>>(
        xbf, w1t, b1, eidx, ew, hbuf, 0, nbm);
    g2<<<dim3(nbm * (D_ / 256)), 512, 131072, stream>>>(
        hbuf, w2t, b2, eidx, ew, out, 0, nbm);
  } else {
    // chunked: [w1t][w2t][xbf_chunk][h_chunk]
    long cap = ((long)ws_size - (long)(2 * WT)) / ((long)(D_ + F_) * 2);
    long chunk = (cap / 256) * 256;
    if (chunk > total_rows) chunk = total_rows;
    if (chunk < 256) chunk = 256;
    unsigned short* xbf = (unsigned short*)(ws + 2 * WT);
    unsigned short* hbuf = xbf + (size_t)chunk * D_;
    for (long r0 = 0; r0 < total_rows; r0 += chunk) {
      long nr = total_rows - r0;
      if (nr > chunk) nr = chunk;
      cvt_bf16_kernel<<<512, 256, 0, stream>>>(x + r0 * D_, xbf, nr * D_ / 4);
      int nbm = (int)(nr / 256);
      g1<<<dim3(nbm * (F_ / 256)), 512, 131072, stream>>>(
          xbf, w1t, b1, eidx, ew, hbuf, (int)r0, nbm);
      g2<<<dim3(nbm * (D_ / 256)), 512, 131072, stream>>>(
          hbuf, w2t, b2, eidx, ew, out + r0 * D_, (int)r0, nbm);
    }
  }
}

// Round 5
// 708.585 us; speedup vs baseline: 1.8465x; 1.0110x over previous
//
#include <hip/hip_runtime.h>
#include <hip/hip_bf16.h>

// MoE expert MLP: y[b] = (gelu(x[b] @ W1[e] + b1[e]) @ W2[e] + b2[e]) * w[b]
// B=8, S=4096, D=1024, F=4096, E=8. f32 in/out; bf16 MFMA, 256^2 8-phase.

#define B_ 8
#define S_ 4096
#define D_ 1024
#define F_ 4096
#define E_ 8

typedef __bf16 bf16x8 __attribute__((ext_vector_type(8)));
typedef float f32x4 __attribute__((ext_vector_type(4)));

__device__ __forceinline__ unsigned short f2bf(float f) {
  unsigned u = __float_as_uint(f);
  u += 0x7FFFu + ((u >> 16) & 1u);   // round-to-nearest-even
  return (unsigned short)(u >> 16);
}

#define GLD16(g, l) __builtin_amdgcn_global_load_lds(                         \
    (const __attribute__((address_space(1))) unsigned int*)(g),              \
    (__attribute__((address_space(3))) unsigned int*)(l), 16, 0, 0)

// ---------------------------------------------------------------------------
// Transpose + f32->bf16:  src (nmat, R, C) f32  ->  dst (nmat, C, R) bf16
// ---------------------------------------------------------------------------
__global__ __launch_bounds__(256) void transpose_cvt_kernel(
    const float* __restrict__ src, unsigned short* __restrict__ dst,
    int R, int C) {
  __shared__ float t[32][33];
  const float* s = src + (size_t)blockIdx.z * R * C;
  unsigned short* d = dst + (size_t)blockIdx.z * R * C;
  int c0 = blockIdx.x * 32, r0 = blockIdx.y * 32;
  int x = threadIdx.x, y = threadIdx.y;      // 32 x 8
#pragma unroll
  for (int j = 0; j < 32; j += 8)
    t[y + j][x] = s[(size_t)(r0 + y + j) * C + (c0 + x)];
  __syncthreads();
#pragma unroll
  for (int j = 0; j < 32; j += 8)
    d[(size_t)(c0 + y + j) * R + (r0 + x)] = f2bf(t[x][y + j]);
}

// ---------------------------------------------------------------------------
// f32 -> bf16 flat convert, vectorized
// ---------------------------------------------------------------------------
__global__ __launch_bounds__(256) void cvt_bf16_kernel(
    const float* __restrict__ src, unsigned short* __restrict__ dst, long n4) {
  long i = (long)blockIdx.x * 256 + threadIdx.x;
  long stride = (long)gridDim.x * 256;
  for (; i < n4; i += stride) {
    float4 v = ((const float4*)src)[i];
    uint2 o;
    o.x = (unsigned)f2bf(v.x) | ((unsigned)f2bf(v.y) << 16);
    o.y = (unsigned)f2bf(v.z) | ((unsigned)f2bf(v.w) << 16);
    ((uint2*)dst)[i] = o;
  }
}

// ---------------------------------------------------------------------------
// 256x256-tile 4-phase GEMM, ONE barrier per phase (R5).
//   C[row][col] = A[row][k] * Bw[e][col][k]  (+bias, optional gelu/scale)
//   8 waves (2M x 4N), per-wave 128x64 output, BK=64, mfma 16x16x32 bf16.
//   LDS 128 KiB: buf{0,1} x { A[2 halves 128x64] , B[2 halves 128x64] },
//   16B-chunk XOR swizzle: chunk cc of row r holds global k-chunk cc^(r&7).
//   Phase = { ds_reads, stage-issue, setprio(1), 16 MFMA (compiler inserts
//   counted lgkmcnt), setprio(0), sched_barrier, s_barrier }.
//   NO barrier between reads and MFMA: reads(p) of wave i drain while wave
//   j's MFMA(p) runs — this is the LDS/MFMA overlap the double-barrier
//   lockstep was preventing (R3/R4 plateau at 33% MfmaUtil).
//   Hazards still enforced: every phase's reads are consumed by that phase's
//   MFMA before the phase-end barrier, so staging into retired regions of
//   the live buffer (t+2) cannot land early; vmcnt(6) at ph4 guarantees the
//   next tile's 4 halves have landed before its ph1 reads.
// ---------------------------------------------------------------------------

#define STAGE(cur, op, h, tk, base)                                           \
  {                                                                           \
    const unsigned short* g0_ = (base) + (size_t)((h) * 128 + sr) * LDK +     \
                                (tk) * 64 + sgc * 8;                          \
    GLD16(g0_, smem + (cur) * 65536 + (op) * 32768 + (h) * 16384 +            \
                   wave * 1024);                                              \
    GLD16(g0_ + (size_t)64 * LDK,                                             \
          smem + (cur) * 65536 + (op) * 32768 + (h) * 16384 + 8192 +          \
              wave * 1024);                                                   \
  }

#define LDA_HALF(cur, H)                                                      \
  _Pragma("unroll") for (int m = 0; m < 4; ++m) {                             \
    const char* p_ = smem + (cur) * 65536 + (H) * 16384 +                     \
                     (wr * 64 + m * 16 + l15) * 128;                          \
    aM[m][0] = *(const bf16x8*)(p_ + ca0);                                    \
    aM[m][1] = *(const bf16x8*)(p_ + ca1);                                    \
  }

#define LDB_Q(cur, Q, breg)                                                   \
  _Pragma("unroll") for (int n = 0; n < 2; ++n) {                             \
    const char* p_ = smem + (cur) * 65536 + 32768 + (Q) * 16384 +             \
                     (wc * 32 + n * 16 + l15) * 128;                          \
    breg[n][0] = *(const bf16x8*)(p_ + ca0);                                  \
    breg[n][1] = *(const bf16x8*)(p_ + ca1);                                  \
  }

#define MMA_Q(MB, breg, NB)                                                   \
  _Pragma("unroll") for (int ks = 0; ks < 2; ++ks)                            \
      _Pragma("unroll") for (int m = 0; m < 4; ++m)                           \
          _Pragma("unroll") for (int n = 0; n < 2; ++n)                       \
              acc[(MB) + m][(NB) + n] =                                       \
      __builtin_amdgcn_mfma_f32_16x16x32_bf16(                                \
          aM[m][ks], breg[n][ks], acc[(MB) + m][(NB) + n], 0, 0, 0);

#define PH_END                                                                \
  __builtin_amdgcn_s_setprio(0);                                              \
  __builtin_amdgcn_sched_barrier(0);                                          \
  __builtin_amdgcn_s_barrier();

// MODE: 2 = full staging, 1 = tail-1 (stage Ah1 only, drain), 0 = last tile
#define TILE(cur, t, MODE)                                                    \
  LDA_HALF(cur, 0);                                                           \
  LDB_Q(cur, 0, bq0);                                                         \
  if ((MODE) >= 1) STAGE((cur) ^ 1, 0, 1, (t) + 1, Abase);                    \
  __builtin_amdgcn_s_setprio(1);                                              \
  MMA_Q(0, bq0, 0);                                                           \
  PH_END;                                                                     \
  LDB_Q(cur, 1, bq1);                                                         \
  if ((MODE) == 2) STAGE(cur, 0, 0, (t) + 2, Abase);                          \
  __builtin_amdgcn_s_setprio(1);                                              \
  MMA_Q(0, bq1, 2);                                                           \
  PH_END;                                                                     \
  LDA_HALF(cur, 1);                                                           \
  if ((MODE) == 2) STAGE(cur, 1, 0, (t) + 2, Bbase);                          \
  __builtin_amdgcn_s_setprio(1);                                              \
  MMA_Q(4, bq0, 0);                                                           \
  PH_END;                                                                     \
  if ((MODE) == 2) STAGE(cur, 1, 1, (t) + 2, Bbase);                          \
  __builtin_amdgcn_s_setprio(1);                                              \
  MMA_Q(4, bq1, 2);                                                           \
  __builtin_amdgcn_s_setprio(0);                                              \
  __builtin_amdgcn_sched_barrier(0);                                          \
  if ((MODE) == 2) asm volatile("s_waitcnt vmcnt(6)" ::: "memory");           \
  if ((MODE) == 1) asm volatile("s_waitcnt vmcnt(0)" ::: "memory");           \
  __builtin_amdgcn_s_barrier();

template <int NT, int LDK, int NCOL, bool GELU>
__global__ __launch_bounds__(512, 2) void gemm8p_kernel(
    const unsigned short* __restrict__ A,   // [rows][LDK] bf16 (chunk-local)
    const unsigned short* __restrict__ Bw,  // [E][NCOL][LDK] bf16
    const float* __restrict__ bias,         // [E][NCOL]
    const int* __restrict__ eidx, const float* __restrict__ ew,
    void* __restrict__ Out, int grow0, int nbm) {
  extern __shared__ __align__(16) char smem[];

  const int tid = threadIdx.x;
  const int lane = tid & 63;
  const int wave = tid >> 6;
  const int wr = wave >> 2;         // 0..1 (M)
  const int wc = wave & 3;          // 0..3 (N)
  const int l15 = lane & 15, lhi = lane >> 4;

  const int nwg = nbm * (NCOL / 256);
  int wg = blockIdx.x;
  if ((nwg & 7) == 0) wg = (wg & 7) * (nwg >> 3) + (wg >> 3);  // XCD swizzle
  const int bm = wg % nbm, bn = wg / nbm;

  const int bat = (grow0 + bm * 256) >> 12;
  const int e = eidx[bat];

  const unsigned short* Abase = A + (size_t)bm * 256 * LDK;
  const unsigned short* Bbase =
      Bw + (size_t)e * (F_ * D_) + (size_t)bn * 256 * LDK;

  // staging per-thread constants (swizzled source)
  const int sr = tid >> 3;                  // 0..63 (row within 64-row slab)
  const int sgc = (tid & 7) ^ (sr & 7);     // global 16B chunk for lds chunk
  // ds_read per-thread swizzled chunk offsets (row&7 == l15&7 always)
  const int ca0 = ((lhi ^ (l15 & 7)) << 4);
  const int ca1 = (((4 + lhi) ^ (l15 & 7)) << 4);

  f32x4 acc[8][4] = {};
  bf16x8 aM[4][2], bq0[2][2], bq1[2][2];

  // prologue: tile0 all 4 halves, tile1 first 3 (Ah0,Bh0,Bh1)
  STAGE(0, 0, 0, 0, Abase);
  STAGE(0, 1, 0, 0, Bbase);
  STAGE(0, 1, 1, 0, Bbase);
  STAGE(0, 0, 1, 0, Abase);
  STAGE(1, 0, 0, 1, Abase);
  STAGE(1, 1, 0, 1, Bbase);
  STAGE(1, 1, 1, 1, Bbase);
  asm volatile("s_waitcnt vmcnt(6)" ::: "memory");
  __builtin_amdgcn_s_barrier();

#pragma unroll 1
  for (int t = 0; t < NT - 2; t += 2) {
    TILE(0, t, 2);
    TILE(1, t + 1, 2);
  }
  TILE(0, NT - 2, 1);
  TILE(1, NT - 1, 0);

  // epilogue
  const float scale = GELU ? 1.0f : ew[bat];
#pragma unroll
  for (int n = 0; n < 4; ++n) {
    const int tcol =
        (n < 2 ? wc * 32 + n * 16 : 128 + wc * 32 + (n - 2) * 16) + l15;
    const int col = bn * 256 + tcol;
    const float bv = bias[(size_t)e * NCOL + col];
#pragma unroll
    for (int m = 0; m < 8; ++m) {
      const int trow =
          (m < 4 ? wr * 64 + m * 16 : 128 + wr * 64 + (m - 4) * 16) + lhi * 4;
      const size_t rowb = (size_t)bm * 256 + trow;
#pragma unroll
      for (int r = 0; r < 4; ++r) {
        float v = acc[m][n][r] + bv;
        if (GELU) {
          // tanh-form gelu: v * sigmoid(2 * 0.79788456*(v + 0.044715 v^3))
          float zz = v * (0.79788456080286536f + 0.0356774081f * v * v);
          float g = v / (1.0f + __expf(-2.0f * zz));
          ((unsigned short*)Out)[(rowb + r) * NCOL + col] = f2bf(g);
        } else {
          ((float*)Out)[(rowb + r) * NCOL + col] = v * scale;
        }
      }
    }
  }
}

// ---------------------------------------------------------------------------
extern "C" void kernel_launch(void* const* d_in, const int* in_sizes, int n_in,
                              void* d_out, int out_size, void* d_ws,
                              size_t ws_size, hipStream_t stream) {
  const float* x = (const float*)d_in[0];
  const float* ew = (const float*)d_in[1];
  const float* W1 = (const float*)d_in[2];
  const float* b1 = (const float*)d_in[3];
  const float* W2 = (const float*)d_in[4];
  const float* b2 = (const float*)d_in[5];
  const int* eidx = (const int*)d_in[6];
  float* out = (float*)d_out;

  char* ws = (char*)d_ws;
  const size_t WT = (size_t)E_ * F_ * D_ * 2;  // 64 MiB per transposed weight
  const size_t XB = (size_t)B_ * S_ * D_ * 2;  // 64 MiB bf16 x
  unsigned short* w1t = (unsigned short*)ws;
  unsigned short* w2t = (unsigned short*)(ws + WT);

  auto g1 = gemm8p_kernel<16, D_, F_, true>;
  auto g2 = gemm8p_kernel<64, F_, D_, false>;
  hipFuncSetAttribute((const void*)g1,
                      hipFuncAttributeMaxDynamicSharedMemorySize, 131072);
  hipFuncSetAttribute((const void*)g2,
                      hipFuncAttributeMaxDynamicSharedMemorySize, 131072);

  // weights: W1 (E,D,F)->(E,F,D), W2 (E,F,D)->(E,D,F), bf16
  transpose_cvt_kernel<<<dim3(F_ / 32, D_ / 32, E_), dim3(32, 8), 0, stream>>>(
      W1, w1t, D_, F_);
  transpose_cvt_kernel<<<dim3(D_ / 32, F_ / 32, E_), dim3(32, 8), 0, stream>>>(
      W2, w2t, F_, D_);

  const long total_rows = (long)B_ * S_;  // 32768
  long hcap = ((long)ws_size - (long)(2 * WT + XB)) / ((long)F_ * 2);

  if (hcap >= total_rows) {
    // full: [w1t][w2t][xbf][hbuf]
    unsigned short* xbf = (unsigned short*)(ws + 2 * WT);
    unsigned short* hbuf = (unsigned short*)(ws + 2 * WT + XB);
    cvt_bf16_kernel<<<2048, 256, 0, stream>>>(x, xbf, (long)B_ * S_ * D_ / 4);
    int nbm = (int)(total_rows / 256);
    g1<<<dim3(nbm * (F_ / 256)), 512, 131072, stream>>>(
        xbf, w1t, b1, eidx, ew, hbuf, 0, nbm);
    g2<<<dim3(nbm * (D_ / 256)), 512, 131072, stream>>>(
        hbuf, w2t, b2, eidx, ew, out, 0, nbm);
  } else {
    // chunked: [w1t][w2t][xbf_chunk][h_chunk]
    long cap = ((long)ws_size - (long)(2 * WT)) / ((long)(D_ + F_) * 2);
    long chunk = (cap / 256) * 256;
    if (chunk > total_rows) chunk = total_rows;
    if (chunk < 256) chunk = 256;
    unsigned short* xbf = (unsigned short*)(ws + 2 * WT);
    unsigned short* hbuf = xbf + (size_t)chunk * D_;
    for (long r0 = 0; r0 < total_rows; r0 += chunk) {
      long nr = total_rows - r0;
      if (nr > chunk) nr = chunk;
      cvt_bf16_kernel<<<512, 256, 0, stream>>>(x + r0 * D_, xbf, nr * D_ / 4);
      int nbm = (int)(nr / 256);
      g1<<<dim3(nbm * (F_ / 256)), 512, 131072, stream>>>(
          xbf, w1t, b1, eidx, ew, hbuf, (int)r0, nbm);
      g2<<<dim3(nbm * (D_ / 256)), 512, 131072, stream>>>(
          hbuf, w2t, b2, eidx, ew, out + r0 * D_, (int)r0, nbm);
    }
  }
}